// Round 3
// baseline (1588.405 us; speedup 1.0000x reference)
//
#include <hip/hip_runtime.h>
#include <hip/hip_bf16.h>

typedef __hip_bfloat16 bf16;

#define N_   4
#define C_   256
#define CC_  96
#define HH   128
#define WHH  128
#define HL   64
#define WL   64
#define PH   (HH*WHH)   // 16384
#define PL   (HL*WL)    // 4096

// ---- ws layout (float offsets) ----
#define WF_HRC   16
#define WF_LRC   (WF_HRC+24576)
#define WF_ENC   (WF_LRC+24576)
#define WF_ENC2  (WF_ENC+21600)
#define WF_PROJ  (WF_ENC2+7776)
#define B_HRC    (WF_PROJ+24576)
#define B_LRC    (B_HRC+96)
#define B_ENC    (B_LRC+96)
#define B_ENC2   (B_ENC+25)
#define B_PROJ   (B_ENC2+9)
#define HAM_LF   (B_PROJ+96)
#define HAM_HF   (HAM_LF+25)
#define A_CHR    103488
#define A_CHR2   (A_CHR + 6291456)
#define A_CLR    (A_CHR2 + 6291456)
#define A_MHH    (A_CLR + 1572864)
#define A_MLH    (A_MHH + 589824)
#define A_MASKLR (A_MLH + 1638400)
#define A_MLL    (A_MASKLR + 1638400)
#define A_MHL    (A_MLL + 409600)
#define A_MLRN   (A_MHL + 147456)
#define A_MHRN   (A_MLRN + 1638400)
#define A_LRUP   (A_MHRN + 589824)
#define WS_FLOATS (A_LRUP + 16777216)

#define OUT0_OFF 0L
#define OUT1_OFF 1638400L
#define OUT2_OFF (1638400L + 16777216L)

__device__ __forceinline__ float ldin(const void* p, long i, int isbf) {
    if (isbf) return __bfloat162float(((const bf16*)p)[i]);
    return ((const float*)p)[i];
}

// Detect input dtype: hamming_hfqg center element == 1.0.
// bf16 buffer -> ushort[4] == 0x3F80 ; f32 buffer -> ushort[4] == low half of 0.0064f (0xB717).
__global__ void probe_dtype(const void* hamhf, int* flag) {
    const unsigned short* u = (const unsigned short*)hamhf;
    *flag = (u[4] == 0x3F80u) ? 1 : 0;
}

__global__ void cvt_k(const void* __restrict__ in, float* __restrict__ out, int n,
                      const int* __restrict__ flag) {
    int isbf = *flag;
    int i = blockIdx.x * 256 + threadIdx.x;
    if (i < n) out[i] = ldin(in, i, isbf);
}

// 1x1 conv, raw (bf16-or-f32) input -> f32 scratch. Cin=256, Cout=96 (16 per block.y).
__global__ __launch_bounds__(256) void conv1x1_in(
    const void* __restrict__ x, const float* __restrict__ Wf, const float* __restrict__ bfp,
    float* __restrict__ y, int P, const int* __restrict__ flag)
{
    int isbf = *flag;
    int g = blockIdx.x * 256 + threadIdx.x;
    int n = g / P, p = g - n * P;
    int cc0 = blockIdx.y * 16;
    long xoff = (long)n * C_ * P + p;
    float acc[16];
#pragma unroll
    for (int i = 0; i < 16; i++) acc[i] = 0.f;
    const float* w = Wf + (long)cc0 * C_;
    for (int c = 0; c < C_; ++c) {
        float xv = ldin(x, xoff + (long)c * P, isbf);
#pragma unroll
        for (int i = 0; i < 16; i++) acc[i] = fmaf(w[i * C_ + c], xv, acc[i]);
    }
    float* yb = y + ((long)n * CC_ + cc0) * P + p;
#pragma unroll
    for (int i = 0; i < 16; i++) yb[(long)i * P] = acc[i] + bfp[cc0 + i];
}

// 1x1 proj conv, f32 input -> f32 output.
__global__ __launch_bounds__(256) void conv1x1_proj(
    const float* __restrict__ x, const float* __restrict__ Wf, const float* __restrict__ bfp,
    float* __restrict__ yout, long obase)
{
    int g = blockIdx.x * 256 + threadIdx.x;
    int n = g / PH, p = g - n * PH;
    int cc0 = blockIdx.y * 16;
    const float* xb = x + (long)n * C_ * PH + p;
    float acc[16];
#pragma unroll
    for (int i = 0; i < 16; i++) acc[i] = 0.f;
    const float* w = Wf + (long)cc0 * C_;
    for (int c = 0; c < C_; ++c) {
        float xv = xb[(long)c * PH];
#pragma unroll
        for (int i = 0; i < 16; i++) acc[i] = fmaf(w[i * C_ + c], xv, acc[i]);
    }
    float* yb = yout + obase + ((long)n * CC_ + cc0) * PH + p;
#pragma unroll
    for (int i = 0; i < 16; i++) yb[(long)i * PH] = acc[i] + bfp[cc0 + i];
}

// 3x3 conv pad=1, f32 in/out, Cin=96. 16x16 pixel tile per block, LDS 18x18 staging.
template<int COUT>
__global__ __launch_bounds__(256) void conv3x3_k(
    const float* __restrict__ x, const float* __restrict__ Wf, const float* __restrict__ bfp,
    float* __restrict__ y, int H, int W)
{
    __shared__ float tile[18 * 18];
    int tw = W / 16;
    int bx = blockIdx.x % tw, by = blockIdx.x / tw;
    int n = blockIdx.y;
    int ox = threadIdx.x & 15, oy = threadIdx.x >> 4;
    int gx = bx * 16 + ox, gy = by * 16 + oy;
    const float* xn = x + (long)n * CC_ * H * W;
    float acc[COUT];
#pragma unroll
    for (int o = 0; o < COUT; o++) acc[o] = 0.f;
    for (int c = 0; c < CC_; ++c) {
        const float* xc = xn + (long)c * H * W;
        for (int i = threadIdx.x; i < 324; i += 256) {
            int ty = i / 18, tx = i - ty * 18;
            int sy = by * 16 - 1 + ty, sx = bx * 16 - 1 + tx;
            tile[i] = (sy >= 0 && sy < H && sx >= 0 && sx < W) ? xc[sy * W + sx] : 0.f;
        }
        __syncthreads();
#pragma unroll
        for (int t = 0; t < 9; t++) {
            float xv = tile[(oy + t / 3) * 18 + ox + t % 3];
#pragma unroll
            for (int o = 0; o < COUT; o++)
                acc[o] = fmaf(Wf[(o * CC_ + c) * 9 + t], xv, acc[o]);
        }
        __syncthreads();
    }
    float* yb = y + (((long)n * COUT + 0) * H + gy) * W + gx;
#pragma unroll
    for (int o = 0; o < COUT; o++) yb[(long)o * H * W] = acc[o] + bfp[o];
}

// c_hr2 = 2*c_hr - carafe3x3(c_hr, normalizer(m_hh, ham3)), 128x128, 96 ch.
__global__ __launch_bounds__(256) void carafe3_res(
    const float* __restrict__ x, const float* __restrict__ m, const float* __restrict__ hamf,
    float* __restrict__ y)
{
    __shared__ float tile[18 * 18];
    int bx = blockIdx.x & 7, by = blockIdx.x >> 3;
    int n = blockIdx.y;
    int ox = threadIdx.x & 15, oy = threadIdx.x >> 4;
    int gx = bx * 16 + ox, gy = by * 16 + oy;
    const float* mb = m + ((long)n * 9) * PH + gy * WHH + gx;
    float w[9]; float mx = -1e30f;
#pragma unroll
    for (int t = 0; t < 9; t++) { w[t] = mb[(long)t * PH]; mx = fmaxf(mx, w[t]); }
    float s = 0.f;
#pragma unroll
    for (int t = 0; t < 9; t++) { w[t] = __expf(w[t] - mx) * hamf[t]; s += w[t]; }
    float inv = 1.f / s;
#pragma unroll
    for (int t = 0; t < 9; t++) w[t] *= inv;
    const float* xn = x + (long)n * CC_ * PH;
    float* yn = y + (long)n * CC_ * PH;
    for (int c = 0; c < CC_; ++c) {
        const float* xc = xn + (long)c * PH;
        for (int i = threadIdx.x; i < 324; i += 256) {
            int ty = i / 18, tx = i - ty * 18;
            int sy = by * 16 - 1 + ty, sx = bx * 16 - 1 + tx;
            tile[i] = (sy >= 0 && sy < HH && sx >= 0 && sx < WHH) ? xc[sy * WHH + sx] : 0.f;
        }
        __syncthreads();
        float ctr = tile[(oy + 1) * 18 + ox + 1];
        float acc = 0.f;
#pragma unroll
        for (int t = 0; t < 9; t++) acc = fmaf(tile[(oy + t / 3) * 18 + ox + t % 3], w[t], acc);
        yn[(long)c * PH + gy * WHH + gx] = 2.f * ctr - acc;
        __syncthreads();
    }
}

// mask_lr = m_lh + carafe_up2(m_ll, normalizer(m_lh, ham5)); weights in-register.
__global__ __launch_bounds__(256) void fuse_masklr(
    const float* __restrict__ mlh, const float* __restrict__ mll,
    const float* __restrict__ hamf, float* __restrict__ masklr)
{
    __shared__ float tile[25 * 144];
    int bx = blockIdx.x & 7, by = blockIdx.x >> 3;
    int n = blockIdx.y;
    int ox = threadIdx.x & 15, oy = threadIdx.x >> 4;
    int gx = bx * 16 + ox, gy = by * 16 + oy;
    const float* mb = mlh + (long)n * 25 * PH + gy * WHH + gx;
    float mv[25], w[25]; float mx = -1e30f;
#pragma unroll
    for (int t = 0; t < 25; t++) { mv[t] = mb[(long)t * PH]; mx = fmaxf(mx, mv[t]); }
    float s = 0.f;
#pragma unroll
    for (int t = 0; t < 25; t++) { w[t] = __expf(mv[t] - mx) * hamf[t]; s += w[t]; }
    float inv = 1.f / s;
#pragma unroll
    for (int t = 0; t < 25; t++) w[t] *= inv;
    int iy0 = by * 8 - 2, ix0 = bx * 8 - 2;
    const float* xn = mll + (long)n * 25 * PL;
    for (int i = threadIdx.x; i < 25 * 144; i += 256) {
        int c = i / 144, r = i - c * 144;
        int ty = r / 12, tx = r - ty * 12;
        int sy = iy0 + ty, sx = ix0 + tx;
        tile[i] = (sy >= 0 && sy < HL && sx >= 0 && sx < WL) ? xn[((long)c * HL + sy) * WL + sx] : 0.f;
    }
    __syncthreads();
    int ly = oy >> 1, lx = ox >> 1;
    float* yb = masklr + (long)n * 25 * PH + gy * WHH + gx;
#pragma unroll
    for (int c = 0; c < 25; c++) {
        float acc = mv[c];
        const float* tc = tile + c * 144;
#pragma unroll
        for (int p = 0; p < 5; p++)
#pragma unroll
            for (int q = 0; q < 5; q++)
                acc = fmaf(tc[(ly + p) * 12 + lx + q], w[p * 5 + q], acc);
        yb[(long)c * PH] = acc;
    }
}

// mask_lr_n = normalizer(mask_lr, ham5) -> f32 scratch + f32 output0.
__global__ __launch_bounds__(256) void norm_lr_out(
    const float* __restrict__ masklr, const float* __restrict__ hamf,
    float* __restrict__ mlrn, float* __restrict__ out0)
{
    int g = blockIdx.x * 256 + threadIdx.x;  // over N*PH
    int n = g / PH, p = g - n * PH;
    const float* mb = masklr + (long)n * 25 * PH + p;
    float v[25]; float mx = -1e30f;
#pragma unroll
    for (int t = 0; t < 25; t++) { v[t] = mb[(long)t * PH]; mx = fmaxf(mx, v[t]); }
    float s = 0.f;
#pragma unroll
    for (int t = 0; t < 25; t++) { v[t] = __expf(v[t] - mx) * hamf[t]; s += v[t]; }
    float inv = 1.f / s;
    float* ob = mlrn + (long)n * 25 * PH + p;
    float* o2 = out0 + (long)n * 25 * PH + p;
#pragma unroll
    for (int t = 0; t < 25; t++) {
        float r = v[t] * inv;
        ob[(long)t * PH] = r;
        o2[(long)t * PH] = r;
    }
}

// mask_hr_n = normalizer(m_hh + carafe_up2(m_hl, mask_lr_n), ham3) -> f32 scratch.
__global__ __launch_bounds__(256) void fuse_maskhr(
    const float* __restrict__ mhh, const float* __restrict__ mhl,
    const float* __restrict__ mlrn, const float* __restrict__ hamhf,
    float* __restrict__ mhrn)
{
    __shared__ float tile[9 * 144];
    int bx = blockIdx.x & 7, by = blockIdx.x >> 3;
    int n = blockIdx.y;
    int ox = threadIdx.x & 15, oy = threadIdx.x >> 4;
    int gx = bx * 16 + ox, gy = by * 16 + oy;
    const float* wb = mlrn + (long)n * 25 * PH + gy * WHH + gx;
    float w[25];
#pragma unroll
    for (int t = 0; t < 25; t++) w[t] = wb[(long)t * PH];
    int iy0 = by * 8 - 2, ix0 = bx * 8 - 2;
    const float* xn = mhl + (long)n * 9 * PL;
    for (int i = threadIdx.x; i < 9 * 144; i += 256) {
        int c = i / 144, r = i - c * 144;
        int ty = r / 12, tx = r - ty * 12;
        int sy = iy0 + ty, sx = ix0 + tx;
        tile[i] = (sy >= 0 && sy < HL && sx >= 0 && sx < WL) ? xn[((long)c * HL + sy) * WL + sx] : 0.f;
    }
    __syncthreads();
    int ly = oy >> 1, lx = ox >> 1;
    const float* hb = mhh + (long)n * 9 * PH + gy * WHH + gx;
    float v[9]; float mx = -1e30f;
#pragma unroll
    for (int c = 0; c < 9; c++) {
        float acc = hb[(long)c * PH];
        const float* tc = tile + c * 144;
#pragma unroll
        for (int p = 0; p < 5; p++)
#pragma unroll
            for (int q = 0; q < 5; q++)
                acc = fmaf(tc[(ly + p) * 12 + lx + q], w[p * 5 + q], acc);
        v[c] = acc; mx = fmaxf(mx, acc);
    }
    float s = 0.f;
#pragma unroll
    for (int c = 0; c < 9; c++) { v[c] = __expf(v[c] - mx) * hamhf[c]; s += v[c]; }
    float inv = 1.f / s;
    float* ob = mhrn + (long)n * 9 * PH + gy * WHH + gx;
#pragma unroll
    for (int c = 0; c < 9; c++) ob[(long)c * PH] = v[c] * inv;
}

// hr_out = 2*hr - carafe3x3(hr, mask_hr_n) -> f32 output1. 64 channels per block.z.
__global__ __launch_bounds__(256) void hr_out_k(
    const void* __restrict__ hr, const float* __restrict__ mhrn,
    float* __restrict__ out, long obase, const int* __restrict__ flag)
{
    int isbf = *flag;
    __shared__ float tile[18 * 18];
    int bx = blockIdx.x & 7, by = blockIdx.x >> 3;
    int n = blockIdx.y;
    int c0 = blockIdx.z * 64;
    int ox = threadIdx.x & 15, oy = threadIdx.x >> 4;
    int gx = bx * 16 + ox, gy = by * 16 + oy;
    const float* mb = mhrn + (long)n * 9 * PH + gy * WHH + gx;
    float w[9];
#pragma unroll
    for (int t = 0; t < 9; t++) w[t] = mb[(long)t * PH];
    long xbase = (long)n * C_ * PH;
    for (int c = c0; c < c0 + 64; ++c) {
        long cb = xbase + (long)c * PH;
        for (int i = threadIdx.x; i < 324; i += 256) {
            int ty = i / 18, tx = i - ty * 18;
            int sy = by * 16 - 1 + ty, sx = bx * 16 - 1 + tx;
            tile[i] = (sy >= 0 && sy < HH && sx >= 0 && sx < WHH) ? ldin(hr, cb + sy * WHH + sx, isbf) : 0.f;
        }
        __syncthreads();
        float ctr = tile[(oy + 1) * 18 + ox + 1];
        float acc = 0.f;
#pragma unroll
        for (int t = 0; t < 9; t++) acc = fmaf(tile[(oy + t / 3) * 18 + ox + t % 3], w[t], acc);
        out[obase + cb + gy * WHH + gx] = 2.f * ctr - acc;
        __syncthreads();
    }
}

// lr_up = carafe_up2(lr_feat, mask_lr_n) -> f32 scratch. 64 channels per block.z.
__global__ __launch_bounds__(256) void lr_up_k(
    const void* __restrict__ lrf, const float* __restrict__ mlrn,
    float* __restrict__ lrup, const int* __restrict__ flag)
{
    int isbf = *flag;
    __shared__ float tile[144];
    int bx = blockIdx.x & 7, by = blockIdx.x >> 3;
    int n = blockIdx.y;
    int c0 = blockIdx.z * 64;
    int ox = threadIdx.x & 15, oy = threadIdx.x >> 4;
    int gx = bx * 16 + ox, gy = by * 16 + oy;
    const float* wb = mlrn + (long)n * 25 * PH + gy * WHH + gx;
    float w[25];
#pragma unroll
    for (int t = 0; t < 25; t++) w[t] = wb[(long)t * PH];
    int iy0 = by * 8 - 2, ix0 = bx * 8 - 2;
    int ly = oy >> 1, lx = ox >> 1;
    for (int c = c0; c < c0 + 64; ++c) {
        long cb = ((long)n * C_ + c) * PL;
        for (int i = threadIdx.x; i < 144; i += 256) {
            int ty = i / 12, tx = i - ty * 12;
            int sy = iy0 + ty, sx = ix0 + tx;
            tile[i] = (sy >= 0 && sy < HL && sx >= 0 && sx < WL) ? ldin(lrf, cb + sy * WL + sx, isbf) : 0.f;
        }
        __syncthreads();
        float acc = 0.f;
#pragma unroll
        for (int p = 0; p < 5; p++)
#pragma unroll
            for (int q = 0; q < 5; q++)
                acc = fmaf(tile[(ly + p) * 12 + lx + q], w[p * 5 + q], acc);
        lrup[((long)n * C_ + c) * PH + gy * WHH + gx] = acc;
        __syncthreads();
    }
}

extern "C" void kernel_launch(void* const* d_in, const int* in_sizes, int n_in,
                              void* d_out, int out_size, void* d_ws, size_t ws_size,
                              hipStream_t stream)
{
    if (ws_size < (size_t)WS_FLOATS * 4) return;  // workspace too small (constant per session)

    const void* hr    = d_in[0];
    const void* lrf   = d_in[1];
    const void* Whrc  = d_in[2];
    const void* bhrc  = d_in[3];
    const void* Wlrc  = d_in[4];
    const void* blrc  = d_in[5];
    const void* Wenc  = d_in[6];
    const void* benc  = d_in[7];
    const void* Wenc2 = d_in[8];
    const void* benc2 = d_in[9];
    const void* Wproj = d_in[10];
    const void* bproj = d_in[11];
    const void* hamlf = d_in[12];
    const void* hamhf = d_in[13];

    float* ws = (float*)d_ws;
    int* flag = (int*)d_ws;
    float* out = (float*)d_out;

    probe_dtype<<<1, 1, 0, stream>>>(hamhf, flag);

    auto cvt = [&](const void* in, int off, int n) {
        cvt_k<<<(n + 255) / 256, 256, 0, stream>>>(in, ws + off, n, flag);
    };
    cvt(Whrc, WF_HRC, 24576);  cvt(bhrc, B_HRC, 96);
    cvt(Wlrc, WF_LRC, 24576);  cvt(blrc, B_LRC, 96);
    cvt(Wenc, WF_ENC, 21600);  cvt(benc, B_ENC, 25);
    cvt(Wenc2, WF_ENC2, 7776); cvt(benc2, B_ENC2, 9);
    cvt(Wproj, WF_PROJ, 24576); cvt(bproj, B_PROJ, 96);
    cvt(hamlf, HAM_LF, 25);    cvt(hamhf, HAM_HF, 9);

    // c_hr, c_lr (1x1 compress)
    conv1x1_in<<<dim3(N_ * PH / 256, 6), 256, 0, stream>>>(hr, ws + WF_HRC, ws + B_HRC, ws + A_CHR, PH, flag);
    conv1x1_in<<<dim3(N_ * PL / 256, 6), 256, 0, stream>>>(lrf, ws + WF_LRC, ws + B_LRC, ws + A_CLR, PL, flag);
    // m_hh = conv3x3(c_hr, W_enc2)
    conv3x3_k<9><<<dim3(64, N_), 256, 0, stream>>>(ws + A_CHR, ws + WF_ENC2, ws + B_ENC2, ws + A_MHH, HH, WHH);
    // c_hr2 = 2*c_hr - carafe3(c_hr, norm(m_hh))
    carafe3_res<<<dim3(64, N_), 256, 0, stream>>>(ws + A_CHR, ws + A_MHH, ws + HAM_HF, ws + A_CHR2);
    // m_lh = conv3x3(c_hr2, W_enc); m_ll, m_hl on lr
    conv3x3_k<25><<<dim3(64, N_), 256, 0, stream>>>(ws + A_CHR2, ws + WF_ENC, ws + B_ENC, ws + A_MLH, HH, WHH);
    conv3x3_k<25><<<dim3(16, N_), 256, 0, stream>>>(ws + A_CLR, ws + WF_ENC, ws + B_ENC, ws + A_MLL, HL, WL);
    conv3x3_k<9><<<dim3(16, N_), 256, 0, stream>>>(ws + A_CLR, ws + WF_ENC2, ws + B_ENC2, ws + A_MHL, HL, WL);
    // mask_lr = m_lh + carafe_up2(m_ll, norm(m_lh))
    fuse_masklr<<<dim3(64, N_), 256, 0, stream>>>(ws + A_MLH, ws + A_MLL, ws + HAM_LF, ws + A_MASKLR);
    // mask_lr_n (== mask_lr_init2) -> scratch f32 + output0 f32
    norm_lr_out<<<dim3(N_ * PH / 256), 256, 0, stream>>>(ws + A_MASKLR, ws + HAM_LF, ws + A_MLRN, out);
    // mask_hr_n = norm(m_hh + carafe_up2(m_hl, mask_lr_n))
    fuse_maskhr<<<dim3(64, N_), 256, 0, stream>>>(ws + A_MHH, ws + A_MHL, ws + A_MLRN, ws + HAM_HF, ws + A_MHRN);
    // hr_out -> output1
    hr_out_k<<<dim3(64, N_, 4), 256, 0, stream>>>(hr, ws + A_MHRN, out, OUT1_OFF, flag);
    // lr_up = carafe_up2(lr_feat, mask_lr_n)
    lr_up_k<<<dim3(64, N_, 4), 256, 0, stream>>>(lrf, ws + A_MLRN, ws + A_LRUP, flag);
    // lr_out = conv1x1(lr_up, W_proj) -> output2
    conv1x1_proj<<<dim3(N_ * PH / 256, 6), 256, 0, stream>>>(ws + A_LRUP, ws + WF_PROJ, ws + B_PROJ, out, OUT2_OFF);
}

// Round 4
// 884.257 us; speedup vs baseline: 1.7963x; 1.7963x over previous
//
#include <hip/hip_runtime.h>
#include <hip/hip_bf16.h>

typedef __hip_bfloat16 bf16;

#define N_   4
#define C_   256
#define CC_  96
#define HH   128
#define WHH  128
#define HL   64
#define WL   64
#define PH   (HH*WHH)   // 16384
#define PL   (HL*WL)    // 4096

// ---- ws layout (float offsets) ----
#define WF_HRC   16
#define WF_LRC   (WF_HRC+24576)
#define WF_ENC   (WF_LRC+24576)
#define WF_ENC2  (WF_ENC+21600)
#define WF_PROJ  (WF_ENC2+7776)
#define B_HRC    (WF_PROJ+24576)
#define B_LRC    (B_HRC+96)
#define B_ENC    (B_LRC+96)
#define B_ENC2   (B_ENC+25)
#define B_PROJ   (B_ENC2+9)
#define HAM_LF   (B_PROJ+96)
#define HAM_HF   (HAM_LF+25)
#define A_CHR    103488
#define A_CHR2   (A_CHR + 6291456)
#define A_CLR    (A_CHR2 + 6291456)
#define A_MHH    (A_CLR + 1572864)
#define A_MLH    (A_MHH + 589824)
#define A_MASKLR (A_MLH + 1638400)
#define A_MLL    (A_MASKLR + 1638400)
#define A_MHL    (A_MLL + 409600)
#define A_MLRN   (A_MHL + 147456)
#define A_MHRN   (A_MLRN + 1638400)
#define A_LRUP   (A_MHRN + 589824)
#define WS_FLOATS (A_LRUP + 16777216)

// partial-sum scratch (reused regions; valid by liveness):
//  m_hh partials (4*4*9*16384   = 2,359,296 f) -> A_CHR2 (c_hr2 written later)
//  m_lh partials (4*4*25*16384  = 6,553,600 f) -> A_LRUP+0
//  m_ll partials (8*4*25*4096   = 3,276,800 f) -> A_LRUP+7,000,000
//  m_hl partials (8*4*9*4096    = 1,179,648 f) -> A_LRUP+11,000,000
#define P_MHH  A_CHR2
#define P_MLH  (A_LRUP)
#define P_MLL  (A_LRUP + 7000000)
#define P_MHL  (A_LRUP + 11000000)

#define OUT0_OFF 0L
#define OUT1_OFF 1638400L
#define OUT2_OFF (1638400L + 16777216L)

__device__ __forceinline__ float ldin(const void* p, long i, int isbf) {
    if (isbf) return __bfloat162float(((const bf16*)p)[i]);
    return ((const float*)p)[i];
}

// Detect input dtype: hamming_hfqg center element == 1.0.
__global__ void probe_dtype(const void* hamhf, int* flag) {
    const unsigned short* u = (const unsigned short*)hamhf;
    *flag = (u[4] == 0x3F80u) ? 1 : 0;
}

// Fused weight/bias conversion: 12 segments in one launch.
// mode 0: copy. mode 1: (96,256) -> transposed [c][o] layout.
struct Seg { const void* src; int dst; int n; int mode; };
struct Segs12 { Seg s[12]; };

__global__ __launch_bounds__(256) void cvt_all(Segs12 A, float* ws,
                                               const int* __restrict__ flag, int total) {
    int isbf = *flag;
    int i = blockIdx.x * 256 + threadIdx.x;
    if (i >= total) return;
    int k = 0, j = i;
    while (j >= A.s[k].n) { j -= A.s[k].n; ++k; }
    float v = ldin(A.s[k].src, j, isbf);
    int d;
    if (A.s[k].mode) { int o = j >> 8, c = j & 255; d = A.s[k].dst + c * 96 + o; }
    else d = A.s[k].dst + j;
    ws[d] = v;
}

// 1x1 conv, raw input -> f32 scratch. Cin=256, 48 output channels per block.y.
// Weights transposed [c][96] so each c-iteration reads 48 contiguous floats (s_load).
__global__ __launch_bounds__(256) void conv1x1_in(
    const void* __restrict__ x, const float* __restrict__ WT, const float* __restrict__ bfp,
    float* __restrict__ y, int P, const int* __restrict__ flag)
{
    int isbf = *flag;
    int g = blockIdx.x * 256 + threadIdx.x;
    int n = g / P, p = g - n * P;
    int cc0 = blockIdx.y * 48;
    long xoff = (long)n * C_ * P + p;
    float acc[48];
#pragma unroll
    for (int i = 0; i < 48; i++) acc[i] = 0.f;
    for (int c = 0; c < C_; ++c) {
        float xv = ldin(x, xoff + (long)c * P, isbf);
        const float* wr = WT + c * 96 + cc0;
#pragma unroll
        for (int i = 0; i < 48; i++) acc[i] = fmaf(wr[i], xv, acc[i]);
    }
    float* yb = y + ((long)n * CC_ + cc0) * P + p;
#pragma unroll
    for (int i = 0; i < 48; i++) yb[(long)i * P] = acc[i] + bfp[cc0 + i];
}

// 1x1 proj conv, f32 input -> f32 output (transposed weights).
__global__ __launch_bounds__(256) void conv1x1_proj(
    const float* __restrict__ x, const float* __restrict__ WT, const float* __restrict__ bfp,
    float* __restrict__ yout, long obase)
{
    int g = blockIdx.x * 256 + threadIdx.x;
    int n = g / PH, p = g - n * PH;
    int cc0 = blockIdx.y * 48;
    const float* xb = x + (long)n * C_ * PH + p;
    float acc[48];
#pragma unroll
    for (int i = 0; i < 48; i++) acc[i] = 0.f;
    for (int c = 0; c < C_; ++c) {
        float xv = xb[(long)c * PH];
        const float* wr = WT + c * 96 + cc0;
#pragma unroll
        for (int i = 0; i < 48; i++) acc[i] = fmaf(wr[i], xv, acc[i]);
    }
    float* yb = yout + obase + ((long)n * CC_ + cc0) * PH + p;
#pragma unroll
    for (int i = 0; i < 48; i++) yb[(long)i * PH] = acc[i] + bfp[cc0 + i];
}

// 3x3 conv pad=1, direct, K-split. Each thread: one pixel, all COUT outputs,
// channels [ks*KC, (ks+1)*KC). Partials: part[ks][n][o][p]. No LDS, no syncs.
template<int COUT>
__global__ __launch_bounds__(256) void conv3x3_part_k(
    const float* __restrict__ x, const float* __restrict__ Wf,
    float* __restrict__ part, int H, int W, int KC)
{
    int p = blockIdx.x * 256 + threadIdx.x;
    int n = blockIdx.y, ks = blockIdx.z;
    int HW = H * W;
    int gy = p / W, gx = p - gy * W;
    int c0 = ks * KC;
    const float* xb = x + ((long)n * CC_ + c0) * HW + p;
    float acc[COUT];
#pragma unroll
    for (int o = 0; o < COUT; o++) acc[o] = 0.f;
    for (int c = 0; c < KC; ++c) {
        const float* xc = xb + (long)c * HW;
        float v[9];
#pragma unroll
        for (int t = 0; t < 9; t++) {
            int dy = t / 3 - 1, dx = t % 3 - 1;
            int yy = gy + dy, xx = gx + dx;
            v[t] = (yy >= 0 && yy < H && xx >= 0 && xx < W) ? xc[dy * W + dx] : 0.f;
        }
        const float* wc = Wf + (c0 + c) * 9;   // + o*CC_*9 + t
#pragma unroll
        for (int o = 0; o < COUT; o++)
#pragma unroll
            for (int t = 0; t < 9; t++)
                acc[o] = fmaf(wc[(long)o * CC_ * 9 + t], v[t], acc[o]);
    }
    float* pb = part + ((long)ks * N_ + n) * COUT * HW + p;
#pragma unroll
    for (int o = 0; o < COUT; o++) pb[(long)o * HW] = acc[o];
}

// out[g] = bias[(g/HW)%COUT] + sum_ks part[ks][g]
__global__ __launch_bounds__(256) void reduce_part(
    const float* __restrict__ part, const float* __restrict__ bias,
    float* __restrict__ out, int KS, long kstride, int COUT, int HW, int total)
{
    int g = blockIdx.x * 256 + threadIdx.x;
    if (g >= total) return;
    float s = 0.f;
    for (int k = 0; k < KS; k++) s += part[(long)k * kstride + g];
    out[g] = s + bias[(g / HW) % COUT];
}

// c_hr2 = 2*c_hr - carafe3x3(c_hr, norm(m_hh, ham3)); direct, channel-split.
__global__ __launch_bounds__(256) void carafe3_res_d(
    const float* __restrict__ x, const float* __restrict__ m,
    const float* __restrict__ hamf, float* __restrict__ y, int KC)
{
    int p = blockIdx.x * 256 + threadIdx.x;
    int n = blockIdx.y;
    int c0 = blockIdx.z * KC;
    int gy = p >> 7, gx = p & 127;
    const float* mb = m + (long)n * 9 * PH + p;
    float w[9]; float mx = -1e30f;
#pragma unroll
    for (int t = 0; t < 9; t++) { w[t] = mb[(long)t * PH]; mx = fmaxf(mx, w[t]); }
    float s = 0.f;
#pragma unroll
    for (int t = 0; t < 9; t++) { w[t] = __expf(w[t] - mx) * hamf[t]; s += w[t]; }
    float inv = 1.f / s;
#pragma unroll
    for (int t = 0; t < 9; t++) w[t] *= inv;
    for (int c = c0; c < c0 + KC; ++c) {
        const float* xc = x + ((long)n * CC_ + c) * PH + p;
        float acc = 0.f, ctr = xc[0];
#pragma unroll
        for (int t = 0; t < 9; t++) {
            int dy = t / 3 - 1, dx = t % 3 - 1;
            int yy = gy + dy, xx = gx + dx;
            float v = (yy >= 0 && yy < HH && xx >= 0 && xx < WHH) ? xc[dy * WHH + dx] : 0.f;
            acc = fmaf(v, w[t], acc);
        }
        y[((long)n * CC_ + c) * PH + p] = 2.f * ctr - acc;
    }
}

// mask_lr = m_lh + carafe_up2(m_ll, normalizer(m_lh, ham5)); LDS-staged (unchanged).
__global__ __launch_bounds__(256) void fuse_masklr(
    const float* __restrict__ mlh, const float* __restrict__ mll,
    const float* __restrict__ hamf, float* __restrict__ masklr)
{
    __shared__ float tile[25 * 144];
    int bx = blockIdx.x & 7, by = blockIdx.x >> 3;
    int n = blockIdx.y;
    int ox = threadIdx.x & 15, oy = threadIdx.x >> 4;
    int gx = bx * 16 + ox, gy = by * 16 + oy;
    const float* mb = mlh + (long)n * 25 * PH + gy * WHH + gx;
    float mv[25], w[25]; float mx = -1e30f;
#pragma unroll
    for (int t = 0; t < 25; t++) { mv[t] = mb[(long)t * PH]; mx = fmaxf(mx, mv[t]); }
    float s = 0.f;
#pragma unroll
    for (int t = 0; t < 25; t++) { w[t] = __expf(mv[t] - mx) * hamf[t]; s += w[t]; }
    float inv = 1.f / s;
#pragma unroll
    for (int t = 0; t < 25; t++) w[t] *= inv;
    int iy0 = by * 8 - 2, ix0 = bx * 8 - 2;
    const float* xn = mll + (long)n * 25 * PL;
    for (int i = threadIdx.x; i < 25 * 144; i += 256) {
        int c = i / 144, r = i - c * 144;
        int ty = r / 12, tx = r - ty * 12;
        int sy = iy0 + ty, sx = ix0 + tx;
        tile[i] = (sy >= 0 && sy < HL && sx >= 0 && sx < WL) ? xn[((long)c * HL + sy) * WL + sx] : 0.f;
    }
    __syncthreads();
    int ly = oy >> 1, lx = ox >> 1;
    float* yb = masklr + (long)n * 25 * PH + gy * WHH + gx;
#pragma unroll
    for (int c = 0; c < 25; c++) {
        float acc = mv[c];
        const float* tc = tile + c * 144;
#pragma unroll
        for (int p = 0; p < 5; p++)
#pragma unroll
            for (int q = 0; q < 5; q++)
                acc = fmaf(tc[(ly + p) * 12 + lx + q], w[p * 5 + q], acc);
        yb[(long)c * PH] = acc;
    }
}

// mask_lr_n = normalizer(mask_lr, ham5) -> f32 scratch + f32 output0.
__global__ __launch_bounds__(256) void norm_lr_out(
    const float* __restrict__ masklr, const float* __restrict__ hamf,
    float* __restrict__ mlrn, float* __restrict__ out0)
{
    int g = blockIdx.x * 256 + threadIdx.x;
    int n = g / PH, p = g - n * PH;
    const float* mb = masklr + (long)n * 25 * PH + p;
    float v[25]; float mx = -1e30f;
#pragma unroll
    for (int t = 0; t < 25; t++) { v[t] = mb[(long)t * PH]; mx = fmaxf(mx, v[t]); }
    float s = 0.f;
#pragma unroll
    for (int t = 0; t < 25; t++) { v[t] = __expf(v[t] - mx) * hamf[t]; s += v[t]; }
    float inv = 1.f / s;
    float* ob = mlrn + (long)n * 25 * PH + p;
    float* o2 = out0 + (long)n * 25 * PH + p;
#pragma unroll
    for (int t = 0; t < 25; t++) {
        float r = v[t] * inv;
        ob[(long)t * PH] = r;
        o2[(long)t * PH] = r;
    }
}

// mask_hr_n = normalizer(m_hh + carafe_up2(m_hl, mask_lr_n), ham3) (unchanged).
__global__ __launch_bounds__(256) void fuse_maskhr(
    const float* __restrict__ mhh, const float* __restrict__ mhl,
    const float* __restrict__ mlrn, const float* __restrict__ hamhf,
    float* __restrict__ mhrn)
{
    __shared__ float tile[9 * 144];
    int bx = blockIdx.x & 7, by = blockIdx.x >> 3;
    int n = blockIdx.y;
    int ox = threadIdx.x & 15, oy = threadIdx.x >> 4;
    int gx = bx * 16 + ox, gy = by * 16 + oy;
    const float* wb = mlrn + (long)n * 25 * PH + gy * WHH + gx;
    float w[25];
#pragma unroll
    for (int t = 0; t < 25; t++) w[t] = wb[(long)t * PH];
    int iy0 = by * 8 - 2, ix0 = bx * 8 - 2;
    const float* xn = mhl + (long)n * 9 * PL;
    for (int i = threadIdx.x; i < 9 * 144; i += 256) {
        int c = i / 144, r = i - c * 144;
        int ty = r / 12, tx = r - ty * 12;
        int sy = iy0 + ty, sx = ix0 + tx;
        tile[i] = (sy >= 0 && sy < HL && sx >= 0 && sx < WL) ? xn[((long)c * HL + sy) * WL + sx] : 0.f;
    }
    __syncthreads();
    int ly = oy >> 1, lx = ox >> 1;
    const float* hb = mhh + (long)n * 9 * PH + gy * WHH + gx;
    float v[9]; float mx = -1e30f;
#pragma unroll
    for (int c = 0; c < 9; c++) {
        float acc = hb[(long)c * PH];
        const float* tc = tile + c * 144;
#pragma unroll
        for (int p = 0; p < 5; p++)
#pragma unroll
            for (int q = 0; q < 5; q++)
                acc = fmaf(tc[(ly + p) * 12 + lx + q], w[p * 5 + q], acc);
        v[c] = acc; mx = fmaxf(mx, acc);
    }
    float s = 0.f;
#pragma unroll
    for (int c = 0; c < 9; c++) { v[c] = __expf(v[c] - mx) * hamhf[c]; s += v[c]; }
    float inv = 1.f / s;
    float* ob = mhrn + (long)n * 9 * PH + gy * WHH + gx;
#pragma unroll
    for (int c = 0; c < 9; c++) ob[(long)c * PH] = v[c] * inv;
}

// hr_out = 2*hr - carafe3x3(hr, mask_hr_n) -> f32 output1. Direct, channel-split.
__global__ __launch_bounds__(256) void hr_out_d(
    const void* __restrict__ hr, const float* __restrict__ mhrn,
    float* __restrict__ out, long obase, const int* __restrict__ flag, int KC)
{
    int isbf = *flag;
    int p = blockIdx.x * 256 + threadIdx.x;
    int n = blockIdx.y;
    int c0 = blockIdx.z * KC;
    int gy = p >> 7, gx = p & 127;
    const float* mb = mhrn + (long)n * 9 * PH + p;
    float w[9];
#pragma unroll
    for (int t = 0; t < 9; t++) w[t] = mb[(long)t * PH];
    for (int c = c0; c < c0 + KC; ++c) {
        long cb = ((long)n * C_ + c) * PH + p;
        float ctr = ldin(hr, cb, isbf);
        float acc = 0.f;
#pragma unroll
        for (int t = 0; t < 9; t++) {
            int dy = t / 3 - 1, dx = t % 3 - 1;
            int yy = gy + dy, xx = gx + dx;
            float v = (yy >= 0 && yy < HH && xx >= 0 && xx < WHH) ? ldin(hr, cb + dy * WHH + dx, isbf) : 0.f;
            acc = fmaf(v, w[t], acc);
        }
        out[obase + cb] = 2.f * ctr - acc;
    }
}

// lr_up = carafe_up2(lr_feat, mask_lr_n) -> f32 scratch. Direct, channel-split.
__global__ __launch_bounds__(256) void lr_up_d(
    const void* __restrict__ lrf, const float* __restrict__ mlrn,
    float* __restrict__ lrup, const int* __restrict__ flag, int KC)
{
    int isbf = *flag;
    int p = blockIdx.x * 256 + threadIdx.x;
    int n = blockIdx.y;
    int c0 = blockIdx.z * KC;
    int gy = p >> 7, gx = p & 127;
    const float* wb = mlrn + (long)n * 25 * PH + p;
    float w[25];
#pragma unroll
    for (int t = 0; t < 25; t++) w[t] = wb[(long)t * PH];
    int iy0 = (gy >> 1) - 2, ix0 = (gx >> 1) - 2;
    for (int c = c0; c < c0 + KC; ++c) {
        long cb = ((long)n * C_ + c) * PL;
        float acc = 0.f;
#pragma unroll
        for (int py = 0; py < 5; py++) {
            int yy = iy0 + py;
#pragma unroll
            for (int qx = 0; qx < 5; qx++) {
                int xx = ix0 + qx;
                float v = (yy >= 0 && yy < HL && xx >= 0 && xx < WL) ? ldin(lrf, cb + yy * WL + xx, isbf) : 0.f;
                acc = fmaf(v, w[py * 5 + qx], acc);
            }
        }
        lrup[((long)n * C_ + c) * PH + p] = acc;
    }
}

extern "C" void kernel_launch(void* const* d_in, const int* in_sizes, int n_in,
                              void* d_out, int out_size, void* d_ws, size_t ws_size,
                              hipStream_t stream)
{
    if (ws_size < (size_t)WS_FLOATS * 4) return;

    const void* hr    = d_in[0];
    const void* lrf   = d_in[1];
    const void* Whrc  = d_in[2];
    const void* bhrc  = d_in[3];
    const void* Wlrc  = d_in[4];
    const void* blrc  = d_in[5];
    const void* Wenc  = d_in[6];
    const void* benc  = d_in[7];
    const void* Wenc2 = d_in[8];
    const void* benc2 = d_in[9];
    const void* Wproj = d_in[10];
    const void* bproj = d_in[11];
    const void* hamlf = d_in[12];
    const void* hamhf = d_in[13];

    float* ws = (float*)d_ws;
    int* flag = (int*)d_ws;
    float* out = (float*)d_out;

    probe_dtype<<<1, 1, 0, stream>>>(hamhf, flag);

    Segs12 A;
    A.s[0]  = {Whrc,  WF_HRC,  24576, 1};
    A.s[1]  = {Wlrc,  WF_LRC,  24576, 1};
    A.s[2]  = {Wproj, WF_PROJ, 24576, 1};
    A.s[3]  = {Wenc,  WF_ENC,  21600, 0};
    A.s[4]  = {Wenc2, WF_ENC2, 7776,  0};
    A.s[5]  = {bhrc,  B_HRC,   96,    0};
    A.s[6]  = {blrc,  B_LRC,   96,    0};
    A.s[7]  = {benc,  B_ENC,   25,    0};
    A.s[8]  = {benc2, B_ENC2,  9,     0};
    A.s[9]  = {bproj, B_PROJ,  96,    0};
    A.s[10] = {hamlf, HAM_LF,  25,    0};
    A.s[11] = {hamhf, HAM_HF,  9,     0};
    int cvt_total = 24576*3 + 21600 + 7776 + 96*3 + 25 + 9 + 25 + 9;
    cvt_all<<<(cvt_total + 255) / 256, 256, 0, stream>>>(A, ws, flag, cvt_total);

    // c_hr, c_lr (1x1 compress, transposed weights)
    conv1x1_in<<<dim3(N_ * PH / 256, 2), 256, 0, stream>>>(hr, ws + WF_HRC, ws + B_HRC, ws + A_CHR, PH, flag);
    conv1x1_in<<<dim3(N_ * PL / 256, 2), 256, 0, stream>>>(lrf, ws + WF_LRC, ws + B_LRC, ws + A_CLR, PL, flag);

    // m_hh = conv3x3(c_hr, W_enc2): K-split 4 x 24ch
    conv3x3_part_k<9><<<dim3(PH / 256, N_, 4), 256, 0, stream>>>(ws + A_CHR, ws + WF_ENC2, ws + P_MHH, HH, WHH, 24);
    reduce_part<<<(N_*9*PH + 255) / 256, 256, 0, stream>>>(ws + P_MHH, ws + B_ENC2, ws + A_MHH, 4, (long)N_*9*PH, 9, PH, N_*9*PH);

    // c_hr2 = 2*c_hr - carafe3(c_hr, norm(m_hh))
    carafe3_res_d<<<dim3(PH / 256, N_, 6), 256, 0, stream>>>(ws + A_CHR, ws + A_MHH, ws + HAM_HF, ws + A_CHR2, 16);

    // m_lh = conv3x3(c_hr2, W_enc): K-split 4 x 24ch
    conv3x3_part_k<25><<<dim3(PH / 256, N_, 4), 256, 0, stream>>>(ws + A_CHR2, ws + WF_ENC, ws + P_MLH, HH, WHH, 24);
    reduce_part<<<(N_*25*PH + 255) / 256, 256, 0, stream>>>(ws + P_MLH, ws + B_ENC, ws + A_MLH, 4, (long)N_*25*PH, 25, PH, N_*25*PH);

    // m_ll, m_hl on c_lr (64x64): K-split 8 x 12ch
    conv3x3_part_k<25><<<dim3(PL / 256, N_, 8), 256, 0, stream>>>(ws + A_CLR, ws + WF_ENC, ws + P_MLL, HL, WL, 12);
    reduce_part<<<(N_*25*PL + 255) / 256, 256, 0, stream>>>(ws + P_MLL, ws + B_ENC, ws + A_MLL, 8, (long)N_*25*PL, 25, PL, N_*25*PL);
    conv3x3_part_k<9><<<dim3(PL / 256, N_, 8), 256, 0, stream>>>(ws + A_CLR, ws + WF_ENC2, ws + P_MHL, HL, WL, 12);
    reduce_part<<<(N_*9*PL + 255) / 256, 256, 0, stream>>>(ws + P_MHL, ws + B_ENC2, ws + A_MHL, 8, (long)N_*9*PL, 9, PL, N_*9*PL);

    // mask_lr = m_lh + carafe_up2(m_ll, norm(m_lh))
    fuse_masklr<<<dim3(64, N_), 256, 0, stream>>>(ws + A_MLH, ws + A_MLL, ws + HAM_LF, ws + A_MASKLR);
    // mask_lr_n (== mask_lr_init2) -> scratch f32 + output0 f32
    norm_lr_out<<<dim3(N_ * PH / 256), 256, 0, stream>>>(ws + A_MASKLR, ws + HAM_LF, ws + A_MLRN, out);
    // mask_hr_n = norm(m_hh + carafe_up2(m_hl, mask_lr_n))
    fuse_maskhr<<<dim3(64, N_), 256, 0, stream>>>(ws + A_MHH, ws + A_MHL, ws + A_MLRN, ws + HAM_HF, ws + A_MHRN);
    // hr_out -> output1 (channel-split 8 x 32)
    hr_out_d<<<dim3(PH / 256, N_, 8), 256, 0, stream>>>(hr, ws + A_MHRN, out, OUT1_OFF, flag, 32);
    // lr_up = carafe_up2(lr_feat, mask_lr_n) (channel-split 8 x 32)
    lr_up_d<<<dim3(PH / 256, N_, 8), 256, 0, stream>>>(lrf, ws + A_MLRN, ws + A_LRUP, flag, 32);
    // lr_out = conv1x1(lr_up, W_proj) -> output2
    conv1x1_proj<<<dim3(N_ * PH / 256, 2), 256, 0, stream>>>(ws + A_LRUP, ws + WF_PROJ, ws + B_PROJ, out, OUT2_OFF);
}